// Round 8
// baseline (143.756 us; speedup 1.0000x reference)
//
#include <hip/hip_runtime.h>
#include <math.h>

// Problem constants
#define B_   8
#define L_   256
#define C_   512
#define OUT_ 512

typedef _Float16 half8 __attribute__((ext_vector_type(8)));
typedef _Float16 half4 __attribute__((ext_vector_type(4)));
typedef float    f32x4 __attribute__((ext_vector_type(4)));
typedef float    f32x2 __attribute__((ext_vector_type(2)));

// ---------------------------------------------------------------------------
// Kernel 1: MFMA relu-GEMM projections (f32 in, f16 frags, f32 acc, f16 out).
//   Y[m][n] = sum_k relu(X[m][k]) * W[k][n] + bias[n],  W raw f32 [k][n].
// 32m x 64n tile, KT=32, dbuf LDS, 1 barrier/step, 2 MFMA/wave/step.
// grid (8,64,2) = 1024 blocks (4/CU) for latency hiding, 256 thr.
// W transpose+cvt folded into B-staging (coalesced row reads).
// ---------------------------------------------------------------------------
__global__ __launch_bounds__(256)
void proj_mfma_kernel(const float* __restrict__ xt, const float* __restrict__ Wp,
                      const float* __restrict__ bp,
                      const float* __restrict__ xd, const float* __restrict__ Wc,
                      const float* __restrict__ bc,
                      _Float16* __restrict__ pt, _Float16* __restrict__ pc)
{
    const int which = blockIdx.z;
    const float* __restrict__ X    = which ? xd : xt;
    const float* __restrict__ W    = which ? Wc : Wp;
    const float* __restrict__ bias = which ? bc : bp;
    _Float16*    __restrict__ Y    = which ? pc : pt;

    __shared__ _Float16 Ah[2][32][40];   // [buf][m][k]
    __shared__ _Float16 Bh[2][64][40];   // [buf][n][k]
    __shared__ _Float16 Ot[32][72];      // epilogue staging

    const int tid = threadIdx.x;
    const int m0 = blockIdx.y << 5, n0 = blockIdx.x << 6;
    const int lane = tid & 63, wv = tid >> 6;
    const int l15 = lane & 15, quad = lane >> 4;
    const int mblk = wv & 1, npair = wv >> 1;   // wave -> (m 16-block, n 32-pair)

    // A staging: threads 0..127 (waves 0-1): srow 0..31, 8 k's each
    const int srow = tid >> 2, sch = (tid & 3) << 3;
    const float* Ag = X + (size_t)(m0 + (srow & 31)) * C_ + sch;
    // B staging: all 256: col n0+nl, 8 W-rows each
    const int nl = tid & 63, kseg = tid >> 6;
    const float* Bg = W + (size_t)(kseg << 3) * C_ + n0 + nl;

    float4 a0 = {}, a1 = {};
    if (tid < 128) { a0 = *(const float4*)(Ag); a1 = *(const float4*)(Ag + 4); }
    float wr[8];
    #pragma unroll
    for (int r = 0; r < 8; ++r) wr[r] = Bg[(size_t)r * C_];

    // write buffer 0
    if (tid < 128) {
        half8 av;
        av[0] = (_Float16)fmaxf(a0.x, 0.f); av[1] = (_Float16)fmaxf(a0.y, 0.f);
        av[2] = (_Float16)fmaxf(a0.z, 0.f); av[3] = (_Float16)fmaxf(a0.w, 0.f);
        av[4] = (_Float16)fmaxf(a1.x, 0.f); av[5] = (_Float16)fmaxf(a1.y, 0.f);
        av[6] = (_Float16)fmaxf(a1.z, 0.f); av[7] = (_Float16)fmaxf(a1.w, 0.f);
        *(half8*)&Ah[0][srow][sch] = av;
    }
    {
        half8 bv;
        #pragma unroll
        for (int r = 0; r < 8; ++r) bv[r] = (_Float16)wr[r];
        *(half8*)&Bh[0][nl][kseg << 3] = bv;
    }

    f32x4 acc[2] = {};
    for (int ks = 0; ks < 16; ++ks) {
        const int cur = ks & 1;
        if (ks < 15) {                        // prefetch next K-slab into regs
            Bg += 32 * C_;
            if (tid < 128) {
                Ag += 32;
                a0 = *(const float4*)(Ag);
                a1 = *(const float4*)(Ag + 4);
            }
            #pragma unroll
            for (int r = 0; r < 8; ++r) wr[r] = Bg[(size_t)r * C_];
        }
        __syncthreads();
        half8 af = *(const half8*)&Ah[cur][(mblk << 4) + l15][quad << 3];
        #pragma unroll
        for (int nb = 0; nb < 2; ++nb) {
            half8 bf = *(const half8*)&Bh[cur][(npair << 5) + (nb << 4) + l15][quad << 3];
            acc[nb] = __builtin_amdgcn_mfma_f32_16x16x32_f16(af, bf, acc[nb], 0, 0, 0);
        }
        if (ks < 15) {
            if (tid < 128) {
                half8 av;
                av[0] = (_Float16)fmaxf(a0.x, 0.f); av[1] = (_Float16)fmaxf(a0.y, 0.f);
                av[2] = (_Float16)fmaxf(a0.z, 0.f); av[3] = (_Float16)fmaxf(a0.w, 0.f);
                av[4] = (_Float16)fmaxf(a1.x, 0.f); av[5] = (_Float16)fmaxf(a1.y, 0.f);
                av[6] = (_Float16)fmaxf(a1.z, 0.f); av[7] = (_Float16)fmaxf(a1.w, 0.f);
                *(half8*)&Ah[cur ^ 1][srow][sch] = av;
            }
            half8 bv;
            #pragma unroll
            for (int r = 0; r < 8; ++r) bv[r] = (_Float16)wr[r];
            *(half8*)&Bh[cur ^ 1][nl][kseg << 3] = bv;
        }
    }

    __syncthreads();
    #pragma unroll
    for (int nb = 0; nb < 2; ++nb) {
        const int n = (npair << 5) + (nb << 4) + l15;
        const float bz = bias[n0 + n];
        #pragma unroll
        for (int r = 0; r < 4; ++r)
            Ot[(mblk << 4) + (quad << 2) + r][n] = (_Float16)(acc[nb][r] + bz);
    }
    __syncthreads();
    const int erow = tid >> 3, ech = (tid & 7) << 3;
    *(half8*)&Y[(size_t)(m0 + erow) * C_ + n0 + ech] = *(const half8*)&Ot[erow][ech];
}

// ---------------------------------------------------------------------------
// Kernel 2 (FUSED): per (i-tile 32, j-tile 16, b, c-half):
//  phase 1: dot[i][j] via MFMA (K=512, dbuf, 2 MFMAs on waves 0-1),
//           sigmoid -> ws_ LDS; per-tile score sum -> sums_part (c-half 0 only)
//  phase 2: partial[b][p][c] = sum_{i,j} ws_[j][i] * r(xd[i,c]*xt[j,c]),
//           r = 1/(1+exp2(2*log2e*x)); packed f32 + 1 rcp / 2 elems.
//  (tanh = 1-2r; finalize recovers sum w*tanh = S - 2*sum(w*r).)
// grid (8,16,16) = 2048 blocks x 256 thr -> 8 blocks/CU for trans-latency
// hiding. xtv read in-loop (not an array) to keep VGPR <= 64.
// ---------------------------------------------------------------------------
__device__ __forceinline__ float sigmoid_fast(float z) {
    float e = __builtin_amdgcn_exp2f(-1.4426950408889634f * z);
    return __builtin_amdgcn_rcpf(e + 1.0f);
}

__global__ __launch_bounds__(256, 6)
void cp_scores_kernel(const _Float16* __restrict__ pt, const _Float16* __restrict__ pc,
                      const float* __restrict__ xd, const float* __restrict__ xt,
                      float* __restrict__ partials, float* __restrict__ sums_part)
{
    const int bx = blockIdx.x, by = blockIdx.y;
    const int b = blockIdx.z >> 1, ch = blockIdx.z & 1;
    const int i0 = bx << 5, j0 = by << 4;
    const int tid = threadIdx.x;
    const int lane = tid & 63, wv = tid >> 6;
    const int l15 = lane & 15, quad = lane >> 4;

    __shared__ _Float16 Ah[2][32][40];   // pt rows (i)
    __shared__ _Float16 Bh[2][16][40];   // pc rows (j)
    __shared__ float ws_[16][36];        // [j][i]
    __shared__ float wred[2];

    // ---- phase 1: 32x16 dot tile, MFMA, dbuf ----
    // staging: 48 rows x 32 k halves; threads 0..191 (waves 0-2)
    const int srow = tid >> 2;            // 0..47 (for tid<192)
    const int sch  = (tid & 3) << 3;      // 0,8,16,24
    const _Float16* Sg = ((srow < 32) ? pt + (size_t)(b * L_ + i0 + srow) * C_
                                      : pc + (size_t)(b * L_ + j0 + (srow - 32)) * C_) + sch;

    half8 v = {};
    if (tid < 192) v = *(const half8*)Sg;
    if (tid < 192) {
        if (srow < 32) *(half8*)&Ah[0][srow][sch] = v;
        else           *(half8*)&Bh[0][srow - 32][sch] = v;
    }

    f32x4 acc = {};
    for (int ks = 0; ks < 16; ++ks) {
        const int cur = ks & 1;
        if (ks < 15 && tid < 192) { Sg += 32; v = *(const half8*)Sg; }
        __syncthreads();
        if (wv < 2) {   // waves 0-1 own the 2 16x16 quadrants (m-block = wv)
            half8 af = *(const half8*)&Ah[cur][(wv << 4) + l15][quad << 3];
            half8 bf = *(const half8*)&Bh[cur][l15][quad << 3];
            acc = __builtin_amdgcn_mfma_f32_16x16x32_f16(af, bf, acc, 0, 0, 0);
        }
        if (ks < 15 && tid < 192) {
            if (srow < 32) *(half8*)&Ah[cur ^ 1][srow][sch] = v;
            else           *(half8*)&Bh[cur ^ 1][srow - 32][sch] = v;
        }
    }

    float lsum = 0.f;
    if (wv < 2) {
        // C/D: col(l15) = j, row(quad*4+r) = i within 16-block (i base = wv*16)
        float4 sg;
        sg.x = sigmoid_fast(acc[0]);
        sg.y = sigmoid_fast(acc[1]);
        sg.z = sigmoid_fast(acc[2]);
        sg.w = sigmoid_fast(acc[3]);
        *(float4*)&ws_[l15][(wv << 4) + (quad << 2)] = sg;
        lsum = (sg.x + sg.y) + (sg.z + sg.w);
    }
    #pragma unroll
    for (int off = 32; off; off >>= 1) lsum += __shfl_xor(lsum, off);
    if (wv < 2 && lane == 0) wred[wv] = lsum;
    __syncthreads();                                    // ws_ + wred ready
    if (tid == 0 && ch == 0)
        sums_part[(b << 7) | (bx << 4) | by] = wred[0] + wred[1];

    // ---- phase 2: weighted tanh-r accumulation, thread = channel ----
    const int c = (ch << 8) | tid;
    const float* __restrict__ xdb = xd + (size_t)(b * L_ + i0) * C_ + c;
    const float* __restrict__ xtb = xt + (size_t)(b * L_ + j0) * C_ + c;
    f32x2 xds2[16];
    #pragma unroll
    for (int i = 0; i < 16; ++i) {
        xds2[i].x = xdb[(size_t)(2 * i) * C_]     * 2.8853900817779268f;  // 2*log2(e)
        xds2[i].y = xdb[(size_t)(2 * i + 1) * C_] * 2.8853900817779268f;
    }

    f32x2 acc01 = {0.f, 0.f}, acc23 = {0.f, 0.f};
    #pragma unroll 4
    for (int jj = 0; jj < 16; ++jj) {
        const float xv = xtb[(size_t)jj * C_];           // in-loop: keeps VGPR low
        #pragma unroll
        for (int i = 0; i < 32; i += 4) {
            const float4 w4 = *(const float4*)&ws_[jj][i];   // wave-uniform broadcast
            // pair (i, i+1)
            f32x2 x01 = xds2[i >> 1] * xv;                    // v_pk_mul
            f32x2 e01 = { __builtin_amdgcn_exp2f(x01.x), __builtin_amdgcn_exp2f(x01.y) };
            f32x2 q01 = e01 + 1.0f;                           // v_pk_add
            float rp01 = __builtin_amdgcn_rcpf(q01.x * q01.y);
            f32x2 r01 = rp01 * __builtin_shufflevector(q01, q01, 1, 0);
            f32x2 w01 = { w4.x, w4.y };
            acc01 = w01 * r01 + acc01;                        // v_pk_fma
            // pair (i+2, i+3)
            f32x2 x23 = xds2[(i >> 1) + 1] * xv;
            f32x2 e23 = { __builtin_amdgcn_exp2f(x23.x), __builtin_amdgcn_exp2f(x23.y) };
            f32x2 q23 = e23 + 1.0f;
            float rp23 = __builtin_amdgcn_rcpf(q23.x * q23.y);
            f32x2 r23 = rp23 * __builtin_shufflevector(q23, q23, 1, 0);
            f32x2 w23 = { w4.z, w4.w };
            acc23 = w23 * r23 + acc23;
        }
    }
    const int p = (bx << 4) | by;   // 0..127
    partials[(size_t)((b << 7) | p) * C_ + c] =
        (acc01.x + acc01.y) + (acc23.x + acc23.y);
}

// ---------------------------------------------------------------------------
// Kernel 3: S = sum(scores); cp[b,c] = 1 - 2*(sum_p partial)/S; out = cp@Wf+bf
// grid (8,8), 512 thr. 128 partials / 128 sums per batch.
// ---------------------------------------------------------------------------
__global__ __launch_bounds__(512)
void finalize_kernel(const float* __restrict__ partials, const float* __restrict__ sums_part,
                     const float* __restrict__ Wf, const float* __restrict__ bfv,
                     float* __restrict__ out)
{
    const int b = blockIdx.y;
    const int t = threadIdx.x;
    __shared__ float cp[C_];
    __shared__ float red[512];
    __shared__ float sumsh;

    red[t] = (t < 128) ? sums_part[(b << 7) | t] : 0.f;

    float s = 0.f;
    #pragma unroll
    for (int p = 0; p < 128; ++p)
        s += partials[(size_t)((b << 7) | p) * C_ + t];

    __syncthreads();
    for (int st = 256; st > 0; st >>= 1) {
        if (t < st) red[t] += red[t + st];
        __syncthreads();
    }
    if (t == 0) sumsh = red[0];
    __syncthreads();

    cp[t] = 1.0f - 2.0f * s / sumsh;
    __syncthreads();

    const int o  = ((int)blockIdx.x << 6) | (t & 63);
    const int c0 = (t >> 6) << 6;
    float acc = 0.f;
    #pragma unroll 8
    for (int i = 0; i < 64; ++i) {
        const int cc = c0 + i;
        acc = fmaf(cp[cc], Wf[(size_t)cc * OUT_ + o], acc);
    }
    red[t] = acc;
    __syncthreads();
    if (t < 64) {
        float a = 0.f;
        #pragma unroll
        for (int g = 0; g < 8; ++g) a += red[(g << 6) | t];
        out[(size_t)b * OUT_ + o] = a + bfv[o];
    }
}

// ---------------------------------------------------------------------------
extern "C" void kernel_launch(void* const* d_in, const int* in_sizes, int n_in,
                              void* d_out, int out_size, void* d_ws, size_t ws_size,
                              hipStream_t stream)
{
    const float* xd = (const float*)d_in[0];
    const float* xt = (const float*)d_in[1];
    const float* Wc = (const float*)d_in[2];
    const float* bc = (const float*)d_in[3];
    const float* Wp = (const float*)d_in[4];
    const float* bp = (const float*)d_in[5];
    const float* Wf = (const float*)d_in[6];
    const float* bf = (const float*)d_in[7];
    float* out = (float*)d_out;

    // workspace (~6.1 MB)
    _Float16* pt  = (_Float16*)d_ws;                 // 2 MB
    _Float16* pc  = pt + 1048576;                    // 2 MB
    float* partials  = (float*)(pc + 1048576);       // 8*128*512 fl = 2 MB
    float* sums_part = partials + B_ * 128 * C_;     // 1024 fl

    proj_mfma_kernel<<<dim3(8, 64, 2), 256, 0, stream>>>(xt, Wp, bp, xd, Wc, bc, pt, pc);
    cp_scores_kernel<<<dim3(8, 16, 16), 256, 0, stream>>>(pt, pc, xd, xt, partials, sums_part);
    finalize_kernel<<<dim3(8, 8), 512, 0, stream>>>(partials, sums_part, Wf, bf, out);
}

// Round 9
// 142.235 us; speedup vs baseline: 1.0107x; 1.0107x over previous
//
#include <hip/hip_runtime.h>
#include <math.h>

// Problem constants
#define B_   8
#define L_   256
#define C_   512
#define OUT_ 512

typedef _Float16 half8 __attribute__((ext_vector_type(8)));
typedef float    f32x4 __attribute__((ext_vector_type(4)));
typedef float    f32x2 __attribute__((ext_vector_type(2)));

// ---------------------------------------------------------------------------
// Kernel 1: MFMA relu-GEMM projections (f32 in, f16 frags, f32 acc, f16 out).
//   Y[m][n] = sum_k relu(X[m][k]) * W[k][n] + bias[n],  W raw f32 [k][n].
// EXACT R7 shape: 64x64 tile, KT=32, dbuf, 1 barrier/step, grid (8,32,2).
// ---------------------------------------------------------------------------
__global__ __launch_bounds__(256)
void proj_mfma_kernel(const float* __restrict__ xt, const float* __restrict__ Wp,
                      const float* __restrict__ bp,
                      const float* __restrict__ xd, const float* __restrict__ Wc,
                      const float* __restrict__ bc,
                      _Float16* __restrict__ pt, _Float16* __restrict__ pc)
{
    const int which = blockIdx.z;
    const float* __restrict__ X    = which ? xd : xt;
    const float* __restrict__ W    = which ? Wc : Wp;
    const float* __restrict__ bias = which ? bc : bp;
    _Float16*    __restrict__ Y    = which ? pc : pt;

    __shared__ _Float16 Ah[2][64][40];   // [buf][m][k]
    __shared__ _Float16 Bh[2][64][40];   // [buf][n][k]
    __shared__ _Float16 Ot[64][72];

    const int tid = threadIdx.x;
    const int m0 = blockIdx.y << 6, n0 = blockIdx.x << 6;
    const int lane = tid & 63, wv = tid >> 6;
    const int l15 = lane & 15, quad = lane >> 4;

    const int srow = tid >> 2, sch = (tid & 3) << 3;
    const float* Ag = X + (size_t)(m0 + srow) * C_ + sch;
    const int nl = tid & 63, kseg = tid >> 6;
    const float* Bg = W + (size_t)(kseg << 3) * C_ + n0 + nl;

    float4 a0 = *(const float4*)(Ag);
    float4 a1 = *(const float4*)(Ag + 4);
    float wr[8];
    #pragma unroll
    for (int r = 0; r < 8; ++r) wr[r] = Bg[(size_t)r * C_];

    {
        half8 av;
        av[0] = (_Float16)fmaxf(a0.x, 0.f); av[1] = (_Float16)fmaxf(a0.y, 0.f);
        av[2] = (_Float16)fmaxf(a0.z, 0.f); av[3] = (_Float16)fmaxf(a0.w, 0.f);
        av[4] = (_Float16)fmaxf(a1.x, 0.f); av[5] = (_Float16)fmaxf(a1.y, 0.f);
        av[6] = (_Float16)fmaxf(a1.z, 0.f); av[7] = (_Float16)fmaxf(a1.w, 0.f);
        *(half8*)&Ah[0][srow][sch] = av;
        half8 bv;
        #pragma unroll
        for (int r = 0; r < 8; ++r) bv[r] = (_Float16)wr[r];
        *(half8*)&Bh[0][nl][kseg << 3] = bv;
    }

    f32x4 acc[4] = {};
    for (int ks = 0; ks < 16; ++ks) {
        const int cur = ks & 1;
        if (ks < 15) {
            Ag += 32;
            Bg += 32 * C_;
            a0 = *(const float4*)(Ag);
            a1 = *(const float4*)(Ag + 4);
            #pragma unroll
            for (int r = 0; r < 8; ++r) wr[r] = Bg[(size_t)r * C_];
        }
        __syncthreads();
        half8 af = *(const half8*)&Ah[cur][(wv << 4) + l15][quad << 3];
        #pragma unroll
        for (int nb = 0; nb < 4; ++nb) {
            half8 bf = *(const half8*)&Bh[cur][(nb << 4) + l15][quad << 3];
            acc[nb] = __builtin_amdgcn_mfma_f32_16x16x32_f16(af, bf, acc[nb], 0, 0, 0);
        }
        if (ks < 15) {
            half8 av;
            av[0] = (_Float16)fmaxf(a0.x, 0.f); av[1] = (_Float16)fmaxf(a0.y, 0.f);
            av[2] = (_Float16)fmaxf(a0.z, 0.f); av[3] = (_Float16)fmaxf(a0.w, 0.f);
            av[4] = (_Float16)fmaxf(a1.x, 0.f); av[5] = (_Float16)fmaxf(a1.y, 0.f);
            av[6] = (_Float16)fmaxf(a1.z, 0.f); av[7] = (_Float16)fmaxf(a1.w, 0.f);
            *(half8*)&Ah[cur ^ 1][srow][sch] = av;
            half8 bv;
            #pragma unroll
            for (int r = 0; r < 8; ++r) bv[r] = (_Float16)wr[r];
            *(half8*)&Bh[cur ^ 1][nl][kseg << 3] = bv;
        }
    }

    __syncthreads();
    #pragma unroll
    for (int nb = 0; nb < 4; ++nb) {
        const float bz = bias[n0 + (nb << 4) + l15];
        #pragma unroll
        for (int r = 0; r < 4; ++r)
            Ot[(wv << 4) + (quad << 2) + r][(nb << 4) + l15] = (_Float16)(acc[nb][r] + bz);
    }
    __syncthreads();
    const int erow = tid >> 3, ech = (tid & 7) << 3;
    #pragma unroll
    for (int h = 0; h < 64; h += 32)
        *(half8*)&Y[(size_t)(m0 + erow + h) * C_ + n0 + ech] = *(const half8*)&Ot[erow + h][ech];
}

// ---------------------------------------------------------------------------
// Kernel 2 (FUSED): per (i-tile 32, j-tile 16, b) -- FULL c per block:
//  phase 1: dot[i][j] via MFMA (K=512, dbuf), sigmoid -> ws_ LDS;
//           per-tile score sum -> sums_part
//  phase 2: thread = channel (512 thr): acc = sum_{i,j} ws_[j][i]*r(xd*xt),
//           r = 1/(1+exp2(2*log2e*x)); packed f32 + 1 rcp / 2 elems;
//           atomicAdd into P[b][c] (replaces partials round-trip).
//  (tanh = 1-2r; finalize: sum w*tanh = S - 2*P.)
// grid (8,16,8) = 1024 blocks x 512 thr -> 4 blocks/CU x 8 waves = 32 waves.
// ---------------------------------------------------------------------------
__device__ __forceinline__ float sigmoid_fast(float z) {
    float e = __builtin_amdgcn_exp2f(-1.4426950408889634f * z);
    return __builtin_amdgcn_rcpf(e + 1.0f);
}

__global__ __launch_bounds__(512, 4)
void cp_scores_kernel(const _Float16* __restrict__ pt, const _Float16* __restrict__ pc,
                      const float* __restrict__ xd, const float* __restrict__ xt,
                      float* __restrict__ P, float* __restrict__ sums_part)
{
    const int bx = blockIdx.x, by = blockIdx.y, b = blockIdx.z;
    const int i0 = bx << 5, j0 = by << 4;
    const int tid = threadIdx.x;
    const int lane = tid & 63, wv = tid >> 6;
    const int l15 = lane & 15, quad = lane >> 4;

    __shared__ _Float16 Ah[2][32][40];   // pt rows (i)
    __shared__ _Float16 Bh[2][16][40];   // pc rows (j)
    __shared__ float ws_[16][36];        // [j][i]
    __shared__ float wred[2];

    // ---- phase 1: 32x16 dot tile, MFMA, dbuf; staging threads 0..191 ----
    const int srow = tid >> 2;            // 0..47 for tid<192
    const int sch  = (tid & 3) << 3;      // 0,8,16,24
    const _Float16* Sg = ((srow < 32) ? pt + (size_t)(b * L_ + i0 + srow) * C_
                                      : pc + (size_t)(b * L_ + j0 + (srow - 32)) * C_) + sch;

    half8 v = {};
    if (tid < 192) {
        v = *(const half8*)Sg;
        if (srow < 32) *(half8*)&Ah[0][srow][sch] = v;
        else           *(half8*)&Bh[0][srow - 32][sch] = v;
    }

    f32x4 acc = {};
    for (int ks = 0; ks < 16; ++ks) {
        const int cur = ks & 1;
        if (ks < 15 && tid < 192) { Sg += 32; v = *(const half8*)Sg; }
        __syncthreads();
        if (wv < 2) {   // waves 0-1 own the 2 16x16 quadrants (m-block = wv)
            half8 af = *(const half8*)&Ah[cur][(wv << 4) + l15][quad << 3];
            half8 bf = *(const half8*)&Bh[cur][l15][quad << 3];
            acc = __builtin_amdgcn_mfma_f32_16x16x32_f16(af, bf, acc, 0, 0, 0);
        }
        if (ks < 15 && tid < 192) {
            if (srow < 32) *(half8*)&Ah[cur ^ 1][srow][sch] = v;
            else           *(half8*)&Bh[cur ^ 1][srow - 32][sch] = v;
        }
    }

    float lsum = 0.f;
    if (wv < 2) {
        // C/D: col(l15) = j, row(quad*4+r) = i within 16-block (i base = wv*16)
        float4 sg;
        sg.x = sigmoid_fast(acc[0]);
        sg.y = sigmoid_fast(acc[1]);
        sg.z = sigmoid_fast(acc[2]);
        sg.w = sigmoid_fast(acc[3]);
        *(float4*)&ws_[l15][(wv << 4) + (quad << 2)] = sg;
        lsum = (sg.x + sg.y) + (sg.z + sg.w);
    }
    #pragma unroll
    for (int off = 32; off; off >>= 1) lsum += __shfl_xor(lsum, off);
    if (wv < 2 && lane == 0) wred[wv] = lsum;
    __syncthreads();                                    // ws_ + wred ready
    if (tid == 0)
        sums_part[(b << 7) | (bx << 4) | by] = wred[0] + wred[1];

    // ---- phase 2: weighted tanh-r accumulation, thread = channel ----
    const int c = tid;
    const float* __restrict__ xdb = xd + (size_t)(b * L_ + i0) * C_ + c;
    const float* __restrict__ xtb = xt + (size_t)(b * L_ + j0) * C_ + c;
    f32x2 xds2[16];
    #pragma unroll
    for (int i = 0; i < 16; ++i) {
        xds2[i].x = xdb[(size_t)(2 * i) * C_]     * 2.8853900817779268f;  // 2*log2(e)
        xds2[i].y = xdb[(size_t)(2 * i + 1) * C_] * 2.8853900817779268f;
    }

    f32x2 acc01 = {0.f, 0.f}, acc23 = {0.f, 0.f};
    #pragma unroll 4
    for (int jj = 0; jj < 16; ++jj) {
        const float xv = xtb[(size_t)jj * C_];
        #pragma unroll
        for (int i = 0; i < 32; i += 4) {
            const float4 w4 = *(const float4*)&ws_[jj][i];   // wave-uniform broadcast
            // pair (i, i+1)
            f32x2 x01 = xds2[i >> 1] * xv;                    // v_pk_mul
            f32x2 e01 = { __builtin_amdgcn_exp2f(x01.x), __builtin_amdgcn_exp2f(x01.y) };
            f32x2 q01 = e01 + 1.0f;                           // v_pk_add
            float rp01 = __builtin_amdgcn_rcpf(q01.x * q01.y);
            f32x2 r01 = rp01 * __builtin_shufflevector(q01, q01, 1, 0);
            f32x2 w01 = { w4.x, w4.y };
            acc01 = w01 * r01 + acc01;                        // v_pk_fma
            // pair (i+2, i+3)
            f32x2 x23 = xds2[(i >> 1) + 1] * xv;
            f32x2 e23 = { __builtin_amdgcn_exp2f(x23.x), __builtin_amdgcn_exp2f(x23.y) };
            f32x2 q23 = e23 + 1.0f;
            float rp23 = __builtin_amdgcn_rcpf(q23.x * q23.y);
            f32x2 r23 = rp23 * __builtin_shufflevector(q23, q23, 1, 0);
            f32x2 w23 = { w4.z, w4.w };
            acc23 = w23 * r23 + acc23;
        }
    }
    atomicAdd(&P[(b << 9) | c], (acc01.x + acc01.y) + (acc23.x + acc23.y));
}

// ---------------------------------------------------------------------------
// Kernel 3 (slim): S_b = sum(sums_part); cp[c] = 1 - 2*P[b][c]/S_b;
//   out[b][o] = sum_c cp[c]*Wf[c][o] + bf[o].
// grid (8 o-tiles, 8 b), 256 thr: t&63 = o-lane, t>>6 = cseg (4 x 128 c).
// ---------------------------------------------------------------------------
__global__ __launch_bounds__(256)
void finalize_kernel(const float* __restrict__ P, const float* __restrict__ sums_part,
                     const float* __restrict__ Wf, const float* __restrict__ bfv,
                     float* __restrict__ out)
{
    const int b = blockIdx.y;
    const int t = threadIdx.x;
    __shared__ float cp[C_];
    __shared__ float red[256];
    __shared__ float sumsh;

    red[t] = (t < 128) ? sums_part[(b << 7) | t] : 0.f;
    __syncthreads();
    for (int st = 64; st > 0; st >>= 1) {
        if (t < st) red[t] += red[t + st] + ((st == 64) ? red[t + 128] : 0.f);
        __syncthreads();
    }
    if (t == 0) sumsh = red[0];
    __syncthreads();

    const float inv = 2.0f / sumsh;
    cp[t]       = 1.0f - P[(b << 9) | t] * inv;
    cp[t + 256] = 1.0f - P[(b << 9) | (t + 256)] * inv;
    __syncthreads();

    const int o    = ((int)blockIdx.x << 6) | (t & 63);
    const int cbase = (t >> 6) << 7;   // 0,128,256,384
    float acc = 0.f;
    #pragma unroll 8
    for (int i = 0; i < 128; ++i) {
        const int cc = cbase + i;
        acc = fmaf(cp[cc], Wf[(size_t)cc * OUT_ + o], acc);
    }
    red[t] = acc;
    __syncthreads();
    if (t < 64) {
        float a = ((red[t] + red[t + 64]) + (red[t + 128] + red[t + 192]));
        out[(size_t)b * OUT_ + o] = a + bfv[o];
    }
}

// ---------------------------------------------------------------------------
extern "C" void kernel_launch(void* const* d_in, const int* in_sizes, int n_in,
                              void* d_out, int out_size, void* d_ws, size_t ws_size,
                              hipStream_t stream)
{
    const float* xd = (const float*)d_in[0];
    const float* xt = (const float*)d_in[1];
    const float* Wc = (const float*)d_in[2];
    const float* bc = (const float*)d_in[3];
    const float* Wp = (const float*)d_in[4];
    const float* bp = (const float*)d_in[5];
    const float* Wf = (const float*)d_in[6];
    const float* bf = (const float*)d_in[7];
    float* out = (float*)d_out;

    // workspace (~4 MB)
    _Float16* pt  = (_Float16*)d_ws;                 // 2 MB
    _Float16* pc  = pt + 1048576;                    // 2 MB
    float* P         = (float*)(pc + 1048576);       // 8*512 fl = 16 KB
    float* sums_part = P + B_ * C_;                  // 1024 fl

    hipMemsetAsync(P, 0, B_ * C_ * sizeof(float), stream);
    proj_mfma_kernel<<<dim3(8, 32, 2), 256, 0, stream>>>(xt, Wp, bp, xd, Wc, bc, pt, pc);
    cp_scores_kernel<<<dim3(8, 16, 8), 512, 0, stream>>>(pt, pc, xd, xt, P, sums_part);
    finalize_kernel<<<dim3(8, 8), 256, 0, stream>>>(P, sums_part, Wf, bf, out);
}

// Round 10
// 140.934 us; speedup vs baseline: 1.0200x; 1.0092x over previous
//
#include <hip/hip_runtime.h>
#include <math.h>

// Problem constants
#define B_   8
#define L_   256
#define C_   512
#define OUT_ 512

typedef _Float16 half8 __attribute__((ext_vector_type(8)));
typedef float    f32x4 __attribute__((ext_vector_type(4)));
typedef float    f32x2 __attribute__((ext_vector_type(2)));

// ---------------------------------------------------------------------------
// Kernel 1: MFMA relu-GEMM projections (f32 in, f16 frags, f32 acc, f16 out).
//   Y[m][n] = sum_k relu(X[m][k]) * W[k][n] + bias[n],  W raw f32 [k][n].
// 64x64 tile, KT=32, dbuf, 1 barrier/step, grid (8,32,2).
// Also zeroes the P accumulator (8 blocks) -- replaces a memset dispatch.
// ---------------------------------------------------------------------------
__global__ __launch_bounds__(256)
void proj_mfma_kernel(const float* __restrict__ xt, const float* __restrict__ Wp,
                      const float* __restrict__ bp,
                      const float* __restrict__ xd, const float* __restrict__ Wc,
                      const float* __restrict__ bc,
                      _Float16* __restrict__ pt, _Float16* __restrict__ pc,
                      float* __restrict__ P)
{
    const int which = blockIdx.z;
    const float* __restrict__ X    = which ? xd : xt;
    const float* __restrict__ W    = which ? Wc : Wp;
    const float* __restrict__ bias = which ? bc : bp;
    _Float16*    __restrict__ Y    = which ? pc : pt;

    // fold P-zeroing into this kernel (stream order guarantees it precedes cp)
    if (which == 0 && blockIdx.y == 0) {
        const int pb = (int)blockIdx.x << 9;
        P[pb | threadIdx.x]         = 0.f;
        P[pb | (threadIdx.x + 256)] = 0.f;
    }

    __shared__ _Float16 Ah[2][64][40];   // [buf][m][k]
    __shared__ _Float16 Bh[2][64][40];   // [buf][n][k]
    __shared__ _Float16 Ot[64][72];

    const int tid = threadIdx.x;
    const int m0 = blockIdx.y << 6, n0 = blockIdx.x << 6;
    const int lane = tid & 63, wv = tid >> 6;
    const int l15 = lane & 15, quad = lane >> 4;

    const int srow = tid >> 2, sch = (tid & 3) << 3;
    const float* Ag = X + (size_t)(m0 + srow) * C_ + sch;
    const int nl = tid & 63, kseg = tid >> 6;
    const float* Bg = W + (size_t)(kseg << 3) * C_ + n0 + nl;

    float4 a0 = *(const float4*)(Ag);
    float4 a1 = *(const float4*)(Ag + 4);
    float wr[8];
    #pragma unroll
    for (int r = 0; r < 8; ++r) wr[r] = Bg[(size_t)r * C_];

    {
        half8 av;
        av[0] = (_Float16)fmaxf(a0.x, 0.f); av[1] = (_Float16)fmaxf(a0.y, 0.f);
        av[2] = (_Float16)fmaxf(a0.z, 0.f); av[3] = (_Float16)fmaxf(a0.w, 0.f);
        av[4] = (_Float16)fmaxf(a1.x, 0.f); av[5] = (_Float16)fmaxf(a1.y, 0.f);
        av[6] = (_Float16)fmaxf(a1.z, 0.f); av[7] = (_Float16)fmaxf(a1.w, 0.f);
        *(half8*)&Ah[0][srow][sch] = av;
        half8 bv;
        #pragma unroll
        for (int r = 0; r < 8; ++r) bv[r] = (_Float16)wr[r];
        *(half8*)&Bh[0][nl][kseg << 3] = bv;
    }

    f32x4 acc[4] = {};
    for (int ks = 0; ks < 16; ++ks) {
        const int cur = ks & 1;
        if (ks < 15) {
            Ag += 32;
            Bg += 32 * C_;
            a0 = *(const float4*)(Ag);
            a1 = *(const float4*)(Ag + 4);
            #pragma unroll
            for (int r = 0; r < 8; ++r) wr[r] = Bg[(size_t)r * C_];
        }
        __syncthreads();
        half8 af = *(const half8*)&Ah[cur][(wv << 4) + l15][quad << 3];
        #pragma unroll
        for (int nb = 0; nb < 4; ++nb) {
            half8 bf = *(const half8*)&Bh[cur][(nb << 4) + l15][quad << 3];
            acc[nb] = __builtin_amdgcn_mfma_f32_16x16x32_f16(af, bf, acc[nb], 0, 0, 0);
        }
        if (ks < 15) {
            half8 av;
            av[0] = (_Float16)fmaxf(a0.x, 0.f); av[1] = (_Float16)fmaxf(a0.y, 0.f);
            av[2] = (_Float16)fmaxf(a0.z, 0.f); av[3] = (_Float16)fmaxf(a0.w, 0.f);
            av[4] = (_Float16)fmaxf(a1.x, 0.f); av[5] = (_Float16)fmaxf(a1.y, 0.f);
            av[6] = (_Float16)fmaxf(a1.z, 0.f); av[7] = (_Float16)fmaxf(a1.w, 0.f);
            *(half8*)&Ah[cur ^ 1][srow][sch] = av;
            half8 bv;
            #pragma unroll
            for (int r = 0; r < 8; ++r) bv[r] = (_Float16)wr[r];
            *(half8*)&Bh[cur ^ 1][nl][kseg << 3] = bv;
        }
    }

    __syncthreads();
    #pragma unroll
    for (int nb = 0; nb < 4; ++nb) {
        const float bz = bias[n0 + (nb << 4) + l15];
        #pragma unroll
        for (int r = 0; r < 4; ++r)
            Ot[(wv << 4) + (quad << 2) + r][(nb << 4) + l15] = (_Float16)(acc[nb][r] + bz);
    }
    __syncthreads();
    const int erow = tid >> 3, ech = (tid & 7) << 3;
    #pragma unroll
    for (int h = 0; h < 64; h += 32)
        *(half8*)&Y[(size_t)(m0 + erow + h) * C_ + n0 + ech] = *(const half8*)&Ot[erow + h][ech];
}

// ---------------------------------------------------------------------------
// Kernel 2 (FUSED): per (i-tile 32, j-tile 16, b), full c per block:
//  phase 1: dot[i][j] via MFMA (K=512, dbuf), sigmoid -> ws_ LDS;
//           per-tile score sum -> sums_part
//  phase 2: thread = channel: acc = sum_{i,j} ws_[j][i]*r(xd*xt),
//           r = 1/(1+exp2(2*log2e*x)); pk f32, 1 rcp / 2 elems; i split in
//           2 halves (xds2[8] live -> low VGPR), xv software-prefetched,
//           4 independent accumulators; atomicAdd into P[b][c].
//  (tanh = 1-2r; finalize: sum w*tanh = S - 2*P.)
// grid (8,16,8) = 1024 blocks x 512 thr (4 blocks/CU x 8 waves = cap).
// ---------------------------------------------------------------------------
__device__ __forceinline__ float sigmoid_fast(float z) {
    float e = __builtin_amdgcn_exp2f(-1.4426950408889634f * z);
    return __builtin_amdgcn_rcpf(e + 1.0f);
}

__global__ __launch_bounds__(512, 4)
void cp_scores_kernel(const _Float16* __restrict__ pt, const _Float16* __restrict__ pc,
                      const float* __restrict__ xd, const float* __restrict__ xt,
                      float* __restrict__ P, float* __restrict__ sums_part)
{
    const int bx = blockIdx.x, by = blockIdx.y, b = blockIdx.z;
    const int i0 = bx << 5, j0 = by << 4;
    const int tid = threadIdx.x;
    const int lane = tid & 63, wv = tid >> 6;
    const int l15 = lane & 15, quad = lane >> 4;

    __shared__ _Float16 Ah[2][32][40];   // pt rows (i)
    __shared__ _Float16 Bh[2][16][40];   // pc rows (j)
    __shared__ float ws_[16][36];        // [j][i]
    __shared__ float wred[2];

    // ---- phase 1: 32x16 dot tile, MFMA, dbuf; staging threads 0..191 ----
    const int srow = tid >> 2;            // 0..47 for tid<192
    const int sch  = (tid & 3) << 3;      // 0,8,16,24
    const _Float16* Sg = ((srow < 32) ? pt + (size_t)(b * L_ + i0 + srow) * C_
                                      : pc + (size_t)(b * L_ + j0 + (srow - 32)) * C_) + sch;

    half8 v = {};
    if (tid < 192) {
        v = *(const half8*)Sg;
        if (srow < 32) *(half8*)&Ah[0][srow][sch] = v;
        else           *(half8*)&Bh[0][srow - 32][sch] = v;
    }

    f32x4 acc = {};
    for (int ks = 0; ks < 16; ++ks) {
        const int cur = ks & 1;
        if (ks < 15 && tid < 192) { Sg += 32; v = *(const half8*)Sg; }
        __syncthreads();
        if (wv < 2) {   // waves 0-1 own the 2 16x16 quadrants (m-block = wv)
            half8 af = *(const half8*)&Ah[cur][(wv << 4) + l15][quad << 3];
            half8 bf = *(const half8*)&Bh[cur][l15][quad << 3];
            acc = __builtin_amdgcn_mfma_f32_16x16x32_f16(af, bf, acc, 0, 0, 0);
        }
        if (ks < 15 && tid < 192) {
            if (srow < 32) *(half8*)&Ah[cur ^ 1][srow][sch] = v;
            else           *(half8*)&Bh[cur ^ 1][srow - 32][sch] = v;
        }
    }

    float lsum = 0.f;
    if (wv < 2) {
        // C/D: col(l15) = j, row(quad*4+r) = i within 16-block (i base = wv*16)
        float4 sg;
        sg.x = sigmoid_fast(acc[0]);
        sg.y = sigmoid_fast(acc[1]);
        sg.z = sigmoid_fast(acc[2]);
        sg.w = sigmoid_fast(acc[3]);
        *(float4*)&ws_[l15][(wv << 4) + (quad << 2)] = sg;
        lsum = (sg.x + sg.y) + (sg.z + sg.w);
    }
    #pragma unroll
    for (int off = 32; off; off >>= 1) lsum += __shfl_xor(lsum, off);
    if (wv < 2 && lane == 0) wred[wv] = lsum;
    __syncthreads();                                    // ws_ + wred ready
    if (tid == 0)
        sums_part[(b << 7) | (bx << 4) | by] = wred[0] + wred[1];

    // ---- phase 2: thread = channel; i split in 2 halves for low VGPR ----
    const int c = tid;
    const float* __restrict__ xdb = xd + (size_t)(b * L_ + i0) * C_ + c;
    const float* __restrict__ xtb = xt + (size_t)(b * L_ + j0) * C_ + c;

    float total = 0.f;
    #pragma unroll
    for (int ih = 0; ih < 2; ++ih) {
        f32x2 xds2[8];                      // 16 live VGPRs only
        #pragma unroll
        for (int i = 0; i < 8; ++i) {
            xds2[i].x = xdb[(size_t)((ih << 4) + 2 * i) * C_]     * 2.8853900817779268f;
            xds2[i].y = xdb[(size_t)((ih << 4) + 2 * i + 1) * C_] * 2.8853900817779268f;
        }
        f32x2 A0 = {0.f, 0.f}, A1 = {0.f, 0.f}, A2 = {0.f, 0.f}, A3 = {0.f, 0.f};
        float xv = xtb[0];
        #pragma unroll 4
        for (int jj = 0; jj < 16; ++jj) {
            const float xv_n = (jj < 15) ? xtb[(size_t)(jj + 1) * C_] : 0.f;  // prefetch
            #pragma unroll
            for (int g = 0; g < 4; ++g) {   // 4 i-groups of 4 within this half
                const float4 w4 = *(const float4*)&ws_[jj][(ih << 4) + (g << 2)];
                const f32x2 xp0 = xds2[(g << 1)];
                const f32x2 xp1 = xds2[(g << 1) + 1];
                // pair (0,1)
                f32x2 x01 = xp0 * xv;
                f32x2 e01 = { __builtin_amdgcn_exp2f(x01.x), __builtin_amdgcn_exp2f(x01.y) };
                f32x2 q01 = e01 + 1.0f;
                float rp01 = __builtin_amdgcn_rcpf(q01.x * q01.y);
                f32x2 r01 = rp01 * __builtin_shufflevector(q01, q01, 1, 0);
                f32x2 w01 = { w4.x, w4.y };
                // pair (2,3)
                f32x2 x23 = xp1 * xv;
                f32x2 e23 = { __builtin_amdgcn_exp2f(x23.x), __builtin_amdgcn_exp2f(x23.y) };
                f32x2 q23 = e23 + 1.0f;
                float rp23 = __builtin_amdgcn_rcpf(q23.x * q23.y);
                f32x2 r23 = rp23 * __builtin_shufflevector(q23, q23, 1, 0);
                f32x2 w23 = { w4.z, w4.w };
                switch (g) {                 // 4 independent fma chains
                    case 0: A0 = w01 * r01 + A0; A1 = w23 * r23 + A1; break;
                    case 1: A2 = w01 * r01 + A2; A3 = w23 * r23 + A3; break;
                    case 2: A0 = w01 * r01 + A0; A1 = w23 * r23 + A1; break;
                    default: A2 = w01 * r01 + A2; A3 = w23 * r23 + A3; break;
                }
            }
            xv = xv_n;
        }
        total += ((A0.x + A0.y) + (A1.x + A1.y)) + ((A2.x + A2.y) + (A3.x + A3.y));
    }
    atomicAdd(&P[(b << 9) | c], total);
}

// ---------------------------------------------------------------------------
// Kernel 3 (slim): S_b = sum(sums_part); cp[c] = 1 - 2*P[b][c]/S_b;
//   out[b][o] = sum_c cp[c]*Wf[c][o] + bf[o].
// grid (8 o-tiles, 8 b), 256 thr.
// ---------------------------------------------------------------------------
__global__ __launch_bounds__(256)
void finalize_kernel(const float* __restrict__ P, const float* __restrict__ sums_part,
                     const float* __restrict__ Wf, const float* __restrict__ bfv,
                     float* __restrict__ out)
{
    const int b = blockIdx.y;
    const int t = threadIdx.x;
    __shared__ float cp[C_];
    __shared__ float red[256];
    __shared__ float sumsh;

    red[t] = (t < 128) ? sums_part[(b << 7) | t] : 0.f;
    __syncthreads();
    for (int st = 64; st > 0; st >>= 1) {
        if (t < st) red[t] += red[t + st] + ((st == 64) ? red[t + 128] : 0.f);
        __syncthreads();
    }
    if (t == 0) sumsh = red[0];
    __syncthreads();

    const float inv = 2.0f / sumsh;
    cp[t]       = 1.0f - P[(b << 9) | t] * inv;
    cp[t + 256] = 1.0f - P[(b << 9) | (t + 256)] * inv;
    __syncthreads();

    const int o     = ((int)blockIdx.x << 6) | (t & 63);
    const int cbase = (t >> 6) << 7;   // 0,128,256,384
    float acc = 0.f;
    #pragma unroll 8
    for (int i = 0; i < 128; ++i) {
        const int cc = cbase + i;
        acc = fmaf(cp[cc], Wf[(size_t)cc * OUT_ + o], acc);
    }
    red[t] = acc;
    __syncthreads();
    if (t < 64) {
        float a = ((red[t] + red[t + 64]) + (red[t + 128] + red[t + 192]));
        out[(size_t)b * OUT_ + o] = a + bfv[o];
    }
}

// ---------------------------------------------------------------------------
extern "C" void kernel_launch(void* const* d_in, const int* in_sizes, int n_in,
                              void* d_out, int out_size, void* d_ws, size_t ws_size,
                              hipStream_t stream)
{
    const float* xd = (const float*)d_in[0];
    const float* xt = (const float*)d_in[1];
    const float* Wc = (const float*)d_in[2];
    const float* bc = (const float*)d_in[3];
    const float* Wp = (const float*)d_in[4];
    const float* bp = (const float*)d_in[5];
    const float* Wf = (const float*)d_in[6];
    const float* bf = (const float*)d_in[7];
    float* out = (float*)d_out;

    // workspace (~4 MB)
    _Float16* pt  = (_Float16*)d_ws;                 // 2 MB
    _Float16* pc  = pt + 1048576;                    // 2 MB
    float* P         = (float*)(pc + 1048576);       // 8*512 fl = 16 KB
    float* sums_part = P + B_ * C_;                  // 1024 fl

    proj_mfma_kernel<<<dim3(8, 32, 2), 256, 0, stream>>>(xt, Wp, bp, xd, Wc, bc, pt, pc, P);
    cp_scores_kernel<<<dim3(8, 16, 8), 512, 0, stream>>>(pt, pc, xd, xt, P, sums_part);
    finalize_kernel<<<dim3(8, 8), 256, 0, stream>>>(P, sums_part, Wf, bf, out);
}